// Round 4
// baseline (484.157 us; speedup 1.0000x reference)
//
#include <hip/hip_runtime.h>
#include <hip/hip_bf16.h>

typedef unsigned short ushortT;
typedef __bf16 bf16x8 __attribute__((ext_vector_type(8)));
typedef float f32x4 __attribute__((ext_vector_type(4)));

#define OUT_SCALE 0.001f

// fast GELU: v * sigmoid(1.5957691*(v + 0.044715 v^3)); |err vs exact| <~1e-3
__device__ __forceinline__ float gelu_fast(float v) {
    const float u = v * fmaf(0.044715f * v, v, 1.0f);
    const float e = __expf(-1.5957691216057308f * u);
    return v * __builtin_amdgcn_rcpf(1.0f + e);
}
__device__ __forceinline__ ushortT f2bf(float f) {
    __hip_bfloat16 h = __float2bfloat16(f);
    return *reinterpret_cast<ushortT*>(&h);
}
__device__ __forceinline__ float bfbits2f(unsigned int hi16) {
    union { unsigned int i; float f; } x; x.i = hi16; return x.f;
}

// ---------------------------------------------------------------------------
// K2: z path. gelu(z + dwconv3x3(z) + b) written as bf16 ZB[b][v][u][c64]
// ---------------------------------------------------------------------------
__global__ __launch_bounds__(256) void k_gelu_z(
    const float* __restrict__ z, const float* __restrict__ wz,
    const float* __restrict__ bz, ushortT* __restrict__ zbuf)
{
    const int b   = blockIdx.x;
    const int tid = threadIdx.x;
    const int c   = tid >> 2;
    const int q   = tid & 3;

    __shared__ float   zs[64 * 260];
    __shared__ ushortT zt[16384];

    {
        const float4* src = (const float4*)(z + ((size_t)b * 64 + c) * 256 + q * 64);
        float4* dstv = (float4*)(zs + c * 260 + q * 64);
        #pragma unroll
        for (int i = 0; i < 16; ++i) dstv[i] = src[i];
    }
    __syncthreads();

    const float* wp = wz + c * 9;
    float w[9];
    #pragma unroll
    for (int i = 0; i < 9; ++i) w[i] = wp[i];
    const float bias = bz[c];
    const float* zc = zs + c * 260;

    for (int v = q * 4; v < q * 4 + 4; ++v) {
        #pragma unroll
        for (int u = 0; u < 16; ++u) {
            float acc = bias;
            #pragma unroll
            for (int dr = 0; dr < 3; ++dr) {
                const int uu = u + dr - 1;
                if (uu < 0 || uu >= 16) continue;
                #pragma unroll
                for (int dc = 0; dc < 3; ++dc) {
                    const int vv = v + dc - 1;
                    if (vv < 0 || vv >= 16) continue;
                    acc += zc[uu * 16 + vv] * w[dr * 3 + dc];
                }
            }
            const float y = acc + zc[u * 16 + v];
            zt[(v * 16 + u) * 64 + c] = f2bf(gelu_fast(y));
        }
    }
    __syncthreads();
    uint4* dst = (uint4*)(zbuf + (size_t)b * 16384);
    const uint4* s4 = (const uint4*)zt;
    for (int i = tid; i < 2048; i += 256) dst[i] = s4[i];
}

// ---------------------------------------------------------------------------
// K_fused: x-path dwconv+gelu fused with correlation.
// Block = (b, row-chunk of 12, channel-half of 32c). 256 threads (4 waves).
// Pipeline/row: prefetch raw x row -> MFMA rowbuf[buf] -> scatter -> xs store
// -> barrier -> conv(next row)->rowbuf[buf^1] -> barrier.
// rowbuf layout [T128][c32], chunk-swizzled: chunk' = chunk ^ ((T>>1)&3).
// xs layout [slot3][c32][106] bf16 (odd word stride -> bank spread).
// ---------------------------------------------------------------------------
__global__ __launch_bounds__(256, 3) void k_fused(
    const float* __restrict__ x, const float* __restrict__ wx,
    const float* __restrict__ bx, const ushortT* __restrict__ zbuf,
    float* __restrict__ out)
{
    const int b     = blockIdx.y;
    const int chunk = blockIdx.x & 7;
    const int chalf = blockIdx.x >> 3;
    const int r0    = chunk * 12;
    const int cbase = chalf * 32;
    const int tid   = threadIdx.x;
    const int wave  = tid >> 6;
    const int lane  = tid & 63;
    const int n     = lane & 15;   // u / m
    const int q     = lane >> 4;   // k-chunk

    __shared__ ushortT xs[3][32][106];     // 20352 B
    __shared__ ushortT rowbuf[2][4096];    // 16384 B  [T128][c32]
    __shared__ float   outacc[27 * 113];   // 12204 B

    // ---- init LDS ----
    for (int i = tid; i < 27 * 113; i += 256) outacc[i] = 0.0f;
    {   // rowbuf pad rows T in [0,8) U [104,128), both buffers: 256 x b128
        const int bufi = tid >> 7, rr8 = (tid >> 2) & 31, c16 = tid & 3;
        const int row = (rr8 < 8) ? rr8 : rr8 + 96;
        uint4 zz = make_uint4(0, 0, 0, 0);
        *(uint4*)(&rowbuf[bufi][row * 32 + c16 * 8]) = zz;
    }
    for (int i = tid; i < 480; i += 256) {  // xs halos: u16 idx {0..3,100..105}
        const int slot = i / 160, rem = i - slot * 160, c = rem / 5, ws = rem - c * 5;
        const int e0 = (ws < 2) ? 2 * ws : 100 + 2 * (ws - 2);
        *(unsigned int*)(&xs[slot][c][e0]) = 0u;
    }

    // ---- B fragments (z) in registers ----
    bf16x8 bfrag[16];
    const ushortT* zb = zbuf + (size_t)b * 16384;
    #pragma unroll
    for (int s = 0; s < 16; ++s)
        bfrag[s] = *(const bf16x8*)(zb + (s * 16 + n) * 64 + cbase + 8 * q);

    // ---- conv weights for my channel ----
    const int cc = tid >> 3, colg = tid & 7;       // conv mapping
    const int cglob = cbase + cc;
    float w[9];
    #pragma unroll
    for (int i = 0; i < 9; ++i) w[i] = wx[cglob * 9 + i];
    const float bias = bx[cglob];
    const int chunkc = cc >> 3, posc = cc & 7;

    // ---- staging helpers ----
    float4 sreg[3];
    const float* xb = x + ((size_t)(b * 64 + cbase)) * 96 * 96;

#define STAGE_LOAD(ROW) do {                                                   \
        _Pragma("unroll")                                                      \
        for (int k_ = 0; k_ < 3; ++k_) {                                       \
            const int idx_ = tid + 256 * k_;                                   \
            const int c_ = idx_ / 24, f4_ = idx_ - c_ * 24;                    \
            float4 v_ = make_float4(0.f, 0.f, 0.f, 0.f);                       \
            if ((ROW) >= 0 && (ROW) < 96)                                      \
                v_ = *(const float4*)(xb + ((size_t)c_ * 96 + (ROW)) * 96 + 4 * f4_); \
            sreg[k_] = v_;                                                     \
        }                                                                      \
    } while (0)
#define STAGE_STORE(SLOT) do {                                                 \
        _Pragma("unroll")                                                      \
        for (int k_ = 0; k_ < 3; ++k_) {                                       \
            const int idx_ = tid + 256 * k_;                                   \
            const int c_ = idx_ / 24, f4_ = idx_ - c_ * 24;                    \
            ushortT* p_ = &xs[SLOT][c_][4 + 4 * f4_];                          \
            unsigned int lo_ = (unsigned int)f2bf(sreg[k_].x)                  \
                             | ((unsigned int)f2bf(sreg[k_].y) << 16);         \
            unsigned int hi_ = (unsigned int)f2bf(sreg[k_].z)                  \
                             | ((unsigned int)f2bf(sreg[k_].w) << 16);         \
            *(unsigned int*)(p_) = lo_;                                        \
            *(unsigned int*)(p_ + 2) = hi_;                                    \
        }                                                                      \
    } while (0)

    // conv of absolute row R into DST; xs slots: (R-1)->(R-r0)%3 etc.
    // slot(row) = (row - r0 + 1) % 3
#define CONV_ROW(R, DST) do {                                                  \
        const int s0_ = ((R) - r0) % 3;      /* slot of R-1 */                 \
        const int s1_ = ((R) - r0 + 1) % 3;  /* slot of R   */                 \
        const int s2_ = ((R) - r0 + 2) % 3;  /* slot of R+1 */                 \
        const ushortT* r0_ = &xs[s0_][cc][0];                                  \
        const ushortT* r1_ = &xs[s1_][cc][0];                                  \
        const ushortT* r2_ = &xs[s2_][cc][0];                                  \
        _Pragma("unroll")                                                      \
        for (int h_ = 0; h_ < 2; ++h_) {                                       \
            const int j0h_ = colg * 12 + h_ * 6;                               \
            const int wb_ = 6 * colg + 3 * h_ + 1;                             \
            float f_[3][10];                                                   \
            const ushortT* rows_[3] = {r0_, r1_, r2_};                         \
            _Pragma("unroll")                                                  \
            for (int k_ = 0; k_ < 3; ++k_) {                                   \
                _Pragma("unroll")                                              \
                for (int p_ = 0; p_ < 5; ++p_) {                               \
                    const unsigned int u_ = *(const unsigned int*)(rows_[k_] + 2 * (wb_ + p_)); \
                    f_[k_][2 * p_]     = bfbits2f(u_ << 16);                   \
                    f_[k_][2 * p_ + 1] = bfbits2f(u_ & 0xFFFF0000u);           \
                }                                                              \
            }                                                                  \
            _Pragma("unroll")                                                  \
            for (int jj_ = 0; jj_ < 6; ++jj_) {                                \
                float acc_ = bias;                                             \
                _Pragma("unroll")                                              \
                for (int k_ = 0; k_ < 3; ++k_)                                 \
                    acc_ += f_[k_][jj_ + 1] * w[k_ * 3]                        \
                          + f_[k_][jj_ + 2] * w[k_ * 3 + 1]                    \
                          + f_[k_][jj_ + 3] * w[k_ * 3 + 2];                   \
                const float y_ = acc_ + f_[1][jj_ + 2];                        \
                const int T_ = j0h_ + jj_ + 8;                                 \
                (DST)[T_ * 32 + ((chunkc ^ ((T_ >> 1) & 3)) << 3) + posc] = f2bf(gelu_fast(y_)); \
            }                                                                  \
        }                                                                      \
    } while (0)

    // ---- prologue: stage rows r0-1, r0, r0+1 into slots 0,1,2 ----
    STAGE_LOAD(r0 - 1); STAGE_STORE(0);
    STAGE_LOAD(r0);     STAGE_STORE(1);
    STAGE_LOAD(r0 + 1); STAGE_STORE(2);
    __syncthreads();
    CONV_ROW(r0, rowbuf[0]);
    __syncthreads();

    // ---- main loop ----
    const int j0a = (wave < 3) ? wave * 32 : 96;
    int buf = 0;
    for (int rr = 0; rr < 12; ++rr) {
        if (rr <= 10) STAGE_LOAD(r0 + rr + 2);   // prefetch (no wait yet)

        f32x4 acc0 = {0.f, 0.f, 0.f, 0.f};
        f32x4 acc1 = {0.f, 0.f, 0.f, 0.f};
        const ushortT* rb = rowbuf[buf];
        const int tb_m = j0a + n;
        #pragma unroll
        for (int s = 0; s < 16; ++s) {
            const int T = tb_m + s;
            const int off = T * 32 + ((q ^ ((T >> 1) & 3)) << 3);
            const bf16x8 a0 = *(const bf16x8*)(rb + off);
            acc0 = __builtin_amdgcn_mfma_f32_16x16x32_bf16(a0, bfrag[s], acc0, 0, 0, 0);
            if (wave < 3) {   // tile j0a+16: swizzle unchanged (+16 -> +8 == 0 mod 4)
                const bf16x8 a1 = *(const bf16x8*)(rb + off + 512);
                acc1 = __builtin_amdgcn_mfma_f32_16x16x32_bf16(a1, bfrag[s], acc1, 0, 0, 0);
            }
        }

        // scatter: C elem (m=q*4+g3, n) -> out row i=(r0+rr)+8-n, col j=j0a+m
        {
            const int ii = rr + 15 - n;
            float* orow = outacc + ii * 113 + j0a + 4 * q;
            #pragma unroll
            for (int g3 = 0; g3 < 4; ++g3) atomicAdd(&orow[g3], acc0[g3]);
            if (wave < 3) {
                #pragma unroll
                for (int g3 = 0; g3 < 4; ++g3) atomicAdd(&orow[16 + g3], acc1[g3]);
            }
        }

        if (rr <= 10) STAGE_STORE(rr % 3);       // slot(r0+rr+2) = (rr+3)%3
        __syncthreads();                          // xs visible, rowbuf[buf] free
        if (rr <= 10) CONV_ROW(r0 + rr + 1, rowbuf[buf ^ 1]);
        __syncthreads();
        buf ^= 1;
    }

    // ---- epilogue: rows [r0-7, r0+19], valid i,j in [0,97) ----
    float* outb = out + (size_t)b * 9409;
    for (int i = tid; i < 27 * 97; i += 256) {
        const int ii = i / 97, j = i - ii * 97;
        const int irow = r0 - 7 + ii;
        if (irow >= 0 && irow < 97)
            atomicAdd(&outb[irow * 97 + j], outacc[ii * 113 + j] * OUT_SCALE);
    }
#undef STAGE_LOAD
#undef STAGE_STORE
#undef CONV_ROW
}

// ---------------------------------------------------------------------------
extern "C" void kernel_launch(void* const* d_in, const int* in_sizes, int n_in,
                              void* d_out, int out_size, void* d_ws, size_t ws_size,
                              hipStream_t stream)
{
    const float* z  = (const float*)d_in[0];
    const float* x  = (const float*)d_in[1];
    const float* wz = (const float*)d_in[2];
    const float* bz = (const float*)d_in[3];
    const float* wx = (const float*)d_in[4];
    const float* bx = (const float*)d_in[5];
    float* out = (float*)d_out;

    ushortT* zbuf = (ushortT*)d_ws;   // 64*16384*2 = 2 MB

    hipMemsetAsync(d_out, 0, (size_t)out_size * 4, stream);

    k_gelu_z<<<dim3(64), 256, 0, stream>>>(z, wz, bz, zbuf);
    k_fused<<<dim3(16, 64), 256, 0, stream>>>(x, wx, bx, zbuf, out);

    (void)in_sizes; (void)n_in; (void)ws_size;
}

// Round 5
// 374.273 us; speedup vs baseline: 1.2936x; 1.2936x over previous
//
#include <hip/hip_runtime.h>
#include <hip/hip_bf16.h>

typedef unsigned short ushortT;
typedef __bf16 bf16x8 __attribute__((ext_vector_type(8)));
typedef float f32x4 __attribute__((ext_vector_type(4)));

#define OUT_SCALE 0.001f

// fast GELU: v * sigmoid(1.5957691*(v + 0.044715 v^3)); |err vs exact| <~1e-3
__device__ __forceinline__ float gelu_fast(float v) {
    const float u = v * fmaf(0.044715f * v, v, 1.0f);
    const float e = __expf(-1.5957691216057308f * u);
    return v * __builtin_amdgcn_rcpf(1.0f + e);
}
__device__ __forceinline__ ushortT f2bf(float f) {
    __hip_bfloat16 h = __float2bfloat16(f);
    return *reinterpret_cast<ushortT*>(&h);
}

// ---------------------------------------------------------------------------
// K1: x path. gelu(x + dwconv3x3(x) + b) -> XgT[b][r][g2][T112][c32 swizzled]
// (chunk' = chunk ^ ((T>>1)&3)).  grid (96,64), 512 thr, thread=(c, 12-col grp).
// No input staging: each thread does 15 predicated float4 global loads (L2
// absorbs the redundancy); LDS only for the 14 KB transpose tile; ONE barrier.
// ---------------------------------------------------------------------------
__global__ __launch_bounds__(512) void k_gelu_x(
    const float* __restrict__ x, const float* __restrict__ wx,
    const float* __restrict__ bx, ushortT* __restrict__ xgt)
{
    const int r = blockIdx.x, b = blockIdx.y, tid = threadIdx.x;
    const int c = tid >> 3, colg = tid & 7, j0 = colg * 12;

    __shared__ ushortT tile[7168];  // [g2][T112][c32] swizzled

    // zero pad bands T in [0,8) and [104,112): 4 regions x 256 elems
    if (tid < 128) {
        const int region = tid >> 5, k = tid & 31;
        const int start = (region & 1) * 3328 + (region >> 1) * 3584;
        *(uint4*)(&tile[start + k * 8]) = make_uint4(0, 0, 0, 0);
    }

    float w[9];
    #pragma unroll
    for (int i = 0; i < 9; ++i) w[i] = wx[c * 9 + i];
    const float bias = bx[c];

    float acc[12], winc[12];
    #pragma unroll
    for (int jj = 0; jj < 12; ++jj) acc[jj] = bias;

    const float* xb = x + (size_t)(b * 64 + c) * 9216;
    #pragma unroll
    for (int dr = 0; dr < 3; ++dr) {
        const int rr = r + dr - 1;
        const bool rok = (rr >= 0) && (rr < 96);
        float f[20];
        #pragma unroll
        for (int m = 0; m < 5; ++m) {
            const int cs = j0 - 4 + 4 * m;
            float4 v = make_float4(0.f, 0.f, 0.f, 0.f);
            if (rok && cs >= 0 && cs <= 92)
                v = *(const float4*)(xb + rr * 96 + cs);
            f[4 * m] = v.x; f[4 * m + 1] = v.y; f[4 * m + 2] = v.z; f[4 * m + 3] = v.w;
        }
        #pragma unroll
        for (int jj = 0; jj < 12; ++jj)
            acc[jj] += f[jj + 3] * w[dr * 3] + f[jj + 4] * w[dr * 3 + 1]
                     + f[jj + 5] * w[dr * 3 + 2];
        if (dr == 1) {
            #pragma unroll
            for (int jj = 0; jj < 12; ++jj) winc[jj] = f[jj + 4];  // residual col
        }
    }

    const int g = c >> 5, cl = c & 31, chunk = cl >> 3, pos = cl & 7;
    #pragma unroll
    for (int jj = 0; jj < 12; ++jj) {
        const float gv = gelu_fast(acc[jj] + winc[jj]);
        const int T = j0 + jj + 8;
        const int schunk = chunk ^ ((T >> 1) & 3);
        tile[g * 3584 + T * 32 + schunk * 8 + pos] = f2bf(gv);
    }
    __syncthreads();

    uint4* dst = (uint4*)(xgt + (size_t)(b * 96 + r) * 7168);
    const uint4* s4 = (const uint4*)tile;
    #pragma unroll
    for (int k = 0; k < 2; ++k) {
        const int i = tid + k * 512;
        if (i < 896) dst[i] = s4[i];
    }
}

// ---------------------------------------------------------------------------
// K2: z path. gelu(z + dwconv3x3(z) + b) written as bf16 ZB[b][v][u][c64]
// ---------------------------------------------------------------------------
__global__ __launch_bounds__(256) void k_gelu_z(
    const float* __restrict__ z, const float* __restrict__ wz,
    const float* __restrict__ bz, ushortT* __restrict__ zbuf)
{
    const int b   = blockIdx.x;
    const int tid = threadIdx.x;
    const int c   = tid >> 2;
    const int q   = tid & 3;

    __shared__ float   zs[64 * 260];
    __shared__ ushortT zt[16384];

    {
        const float4* src = (const float4*)(z + ((size_t)b * 64 + c) * 256 + q * 64);
        float4* dstv = (float4*)(zs + c * 260 + q * 64);
        #pragma unroll
        for (int i = 0; i < 16; ++i) dstv[i] = src[i];
    }
    __syncthreads();

    const float* wp = wz + c * 9;
    float w[9];
    #pragma unroll
    for (int i = 0; i < 9; ++i) w[i] = wp[i];
    const float bias = bz[c];
    const float* zc = zs + c * 260;

    for (int v = q * 4; v < q * 4 + 4; ++v) {
        #pragma unroll
        for (int u = 0; u < 16; ++u) {
            float acc = bias;
            #pragma unroll
            for (int dr = 0; dr < 3; ++dr) {
                const int uu = u + dr - 1;
                if (uu < 0 || uu >= 16) continue;
                #pragma unroll
                for (int dc = 0; dc < 3; ++dc) {
                    const int vv = v + dc - 1;
                    if (vv < 0 || vv >= 16) continue;
                    acc += zc[uu * 16 + vv] * w[dr * 3 + dc];
                }
            }
            const float y = acc + zc[u * 16 + v];
            zt[(v * 16 + u) * 64 + c] = f2bf(gelu_fast(y));
        }
    }
    __syncthreads();
    uint4* dst = (uint4*)(zbuf + (size_t)b * 16384);
    const uint4* s4 = (const uint4*)zt;
    for (int i = tid; i < 2048; i += 256) dst[i] = s4[i];
}

// ---------------------------------------------------------------------------
// K3: correlation, one (b, row) per block. grid (96,64), 256 thr (4 waves).
// Stage row (14336 B) -> barrier -> 7 j-tiles x 32 K-steps MFMA (B-frags in
// 2 g-phases of 16 = 64 VGPR) -> write-once scatter to outacc (no atomics)
// -> barrier -> global atomicAdd of the 16x97 band.
// ---------------------------------------------------------------------------
__global__ __launch_bounds__(256, 4) void k_corr(
    const ushortT* __restrict__ xgt, const ushortT* __restrict__ zbuf,
    float* __restrict__ out)
{
    const int r    = blockIdx.x;
    const int b    = blockIdx.y;
    const int tid  = threadIdx.x;
    const int wave = tid >> 6;
    const int lane = tid & 63;
    const int n    = lane & 15;   // u (B col) == A row within tile
    const int q    = lane >> 4;   // k-chunk / C row-group

    __shared__ ushortT rowbuf[8192];      // [g2][T128][c32 swizzled], 16 KB
    __shared__ float   outacc[16 * 113];  // write-once scatter target

    // zero pad rows T in [112,128) of both groups: 1024 elems = 128 uint4
    if (tid < 128) {
        const int g = tid >> 6, k = tid & 63;
        *(uint4*)(&rowbuf[g * 4096 + 3584 + k * 8]) = make_uint4(0, 0, 0, 0);
    }

    // stage the row: global [g2][T112][c32] -> LDS [g2][T128][c32]
    {
        const uint4* src4 = (const uint4*)(xgt + (size_t)(b * 96 + r) * 7168);
        uint4* rb4 = (uint4*)rowbuf;
        #pragma unroll
        for (int k = 0; k < 4; ++k) {
            const int i2 = tid + k * 256;
            if (i2 < 896) {
                const int dsti = (i2 >= 448) ? i2 + 64 : i2;  // +512 elems for g=1
                rb4[dsti] = src4[i2];
            }
        }
    }
    __syncthreads();

    // MFMA phase: waves 0..2 -> tiles {2w,2w+1}; wave 3 -> tile 6
    const int j0a = (wave < 3) ? wave * 32 : 96;
    const ushortT* zb = zbuf + (size_t)b * 16384;
    const ushortT* rb = rowbuf;
    f32x4 acc0 = {0.f, 0.f, 0.f, 0.f};
    f32x4 acc1 = {0.f, 0.f, 0.f, 0.f};

    #pragma unroll
    for (int g = 0; g < 2; ++g) {
        bf16x8 bfrag[16];
        #pragma unroll
        for (int v = 0; v < 16; ++v)
            bfrag[v] = *(const bf16x8*)(zb + (v * 16 + n) * 64 + g * 32 + 8 * q);
        #pragma unroll
        for (int v = 0; v < 16; ++v) {
            const int T = j0a + n + v;
            const int off = (g * 128 + T) * 32 + ((q ^ ((T >> 1) & 3)) << 3);
            const bf16x8 a0 = *(const bf16x8*)(rb + off);
            acc0 = __builtin_amdgcn_mfma_f32_16x16x32_bf16(a0, bfrag[v], acc0, 0, 0, 0);
            if (wave < 3) {   // tile j0a+16: +16 rows -> +512 elems, same swizzle
                const bf16x8 a1 = *(const bf16x8*)(rb + off + 512);
                acc1 = __builtin_amdgcn_mfma_f32_16x16x32_bf16(a1, bfrag[v], acc1, 0, 0, 0);
            }
        }
    }

    // write-once scatter: C elem (m=4q+g3, u=n) -> outacc[ii=15-u][j=j0a+m]
    {
        const int ii = 15 - n;
        float* orow = outacc + ii * 113 + j0a + 4 * q;
        #pragma unroll
        for (int g3 = 0; g3 < 4; ++g3) orow[g3] = acc0[g3];
        if (wave < 3) {
            #pragma unroll
            for (int g3 = 0; g3 < 4; ++g3) orow[16 + g3] = acc1[g3];
        }
    }
    __syncthreads();

    // epilogue: out[b][i = r-7+ii][j] += outacc[ii][j], i,j valid in [0,97)
    float* outb = out + (size_t)b * 9409;
    #pragma unroll
    for (int p = 0; p < 8; ++p) {
        const int ii = p * 2 + (tid >> 7);
        const int j  = tid & 127;
        const int irow = r - 7 + ii;
        if (j < 97 && irow >= 0 && irow < 97)
            atomicAdd(&outb[irow * 97 + j], outacc[ii * 113 + j] * OUT_SCALE);
    }
}

// ---------------------------------------------------------------------------
extern "C" void kernel_launch(void* const* d_in, const int* in_sizes, int n_in,
                              void* d_out, int out_size, void* d_ws, size_t ws_size,
                              hipStream_t stream)
{
    const float* z  = (const float*)d_in[0];
    const float* x  = (const float*)d_in[1];
    const float* wz = (const float*)d_in[2];
    const float* bz = (const float*)d_in[3];
    const float* wx = (const float*)d_in[4];
    const float* bx = (const float*)d_in[5];
    float* out = (float*)d_out;

    // workspace: XgT (64*96*7168 bf16 = 88.08 MB) then ZB (2 MB)
    ushortT* xgt  = (ushortT*)d_ws;
    ushortT* zbuf = (ushortT*)((char*)d_ws + (size_t)64 * 96 * 7168 * 2);

    hipMemsetAsync(d_out, 0, (size_t)out_size * 4, stream);

    k_gelu_x<<<dim3(96, 64), 512, 0, stream>>>(x, wx, bx, xgt);
    k_gelu_z<<<dim3(64), 256, 0, stream>>>(z, wz, bz, zbuf);
    k_corr<<<dim3(96, 64), 256, 0, stream>>>(xgt, zbuf, out);

    (void)in_sizes; (void)n_in; (void)ws_size;
}